// Round 17
// baseline (242.237 us; speedup 1.0000x reference)
//
#include <hip/hip_runtime.h>
#include <hip/hip_bf16.h>
#include <cstdint>
#include <cstddef>

#define INDIM 256
#define NEG 0.2f

typedef __attribute__((ext_vector_type(8))) short short8v;
typedef __attribute__((ext_vector_type(4))) float f32x4;
typedef __attribute__((ext_vector_type(2))) float f32x2;

__device__ __forceinline__ unsigned short f2bf(float x) {
  __hip_bfloat16 b = __float2bfloat16(x);
  return __builtin_bit_cast(unsigned short, b);
}

// native gfx950 fp8 (OCP E4M3) converts — single VALU instruction each
__device__ __forceinline__ unsigned char f2fp8(float v) {
  int packed = __builtin_amdgcn_cvt_pk_fp8_f32(v, v, 0, false);
  return (unsigned char)(packed & 0xff);
}

__device__ __forceinline__ float lrelu(float v) { return v > 0.f ? v : NEG * v; }

__device__ __forceinline__ short8v ld16(const short* p) {
  return *reinterpret_cast<const short8v*>(p);
}

// ---------------- wprep: W1t, W2t bf16 transposes + xb bf16 concat conversion -------------
__global__ void wprep_kernel(const float* __restrict__ W1, __hip_bfloat16* __restrict__ W1t,
                             const float* __restrict__ W2, __hip_bfloat16* __restrict__ W2t,
                             const float* __restrict__ x1, const float* __restrict__ x2,
                             unsigned short* __restrict__ xb, int N) {
  int idx = blockIdx.x * blockDim.x + threadIdx.x;
  const int T1 = 256 * 384;
  const int T2 = 384 * 128;
  if (idx < T1) {
    int k = idx / 384, c = idx - k * 384;
    W1t[(size_t)c * 256 + k] = __float2bfloat16(W1[idx]);
  } else if (idx < T1 + T2) {
    int i = idx - T1;
    int k = i / 128, c = i - k * 128;
    W2t[(size_t)c * 384 + k] = __float2bfloat16(W2[i]);
  } else {
    int j = idx - T1 - T2;                 // one per 4 elements: row = j>>6, quad = j&63
    if (j < 2 * N * 64) {
      int row = j >> 6, q = j & 63;
      const float* src = (row < N) ? (x1 + (size_t)row * 256) : (x2 + (size_t)(row - N) * 256);
      float4 v = *reinterpret_cast<const float4*>(src + 4 * q);
      uint2 st;
      st.x = (unsigned int)f2bf(v.x) | ((unsigned int)f2bf(v.y) << 16);
      st.y = (unsigned int)f2bf(v.z) | ((unsigned int)f2bf(v.w) << 16);
      *reinterpret_cast<uint2*>(xb + (size_t)row * 256 + 4 * q) = st;
    }
  }
}

// ---------------- GEMM body: DIRECT-FROM-GLOBAL fragments, zero K-loop barriers ----------
// tile 64x128, 4 waves (2x2). Fragment loads are 16B/lane at row*K+k0+lk: each 16-lane
// group reads 16 rows x 64B chunks — coalesced, L2-resident. Register double-buffered.
template<int K, int SST>
__device__ __forceinline__ void gemm_body(int bx, int by,
                                          const short* __restrict__ Ab,
                                          const short* __restrict__ Wt,
                                          const float* __restrict__ att_s,
                                          const float* __restrict__ att_d,
                                          unsigned char* __restrict__ Yc,
                                          float* __restrict__ So,
                                          float* __restrict__ Do,
                                          int M, int NC,
                                          float (*sred)[64]) {
  const int tid = threadIdx.x;
  const int row0 = bx * 64;
  const int col0 = by * 128;
  const int l = tid & 63, w = tid >> 6;
  const int wr = w >> 1, wc = w & 1;
  const int lr = l & 15, lk = (l >> 4) * 8;

  int r0a = row0 + wr * 32 + lr;
  int r1a = r0a + 16;
  const short* pa0 = Ab + (size_t)(r0a < M ? r0a : 0) * K + lk;
  const short* pa1 = Ab + (size_t)(r1a < M ? r1a : 0) * K + lk;
  const short* pb[4];
#pragma unroll
  for (int n = 0; n < 4; ++n)
    pb[n] = Wt + (size_t)(col0 + wc * 64 + n * 16 + lr) * K + lk;

  f32x4 acc[2][4];
#pragma unroll
  for (int m = 0; m < 2; ++m)
#pragma unroll
    for (int n = 0; n < 4; ++n) acc[m][n] = {0.f, 0.f, 0.f, 0.f};

  short8v a0 = ld16(pa0), a1 = ld16(pa1);
  short8v b0 = ld16(pb[0]), b1 = ld16(pb[1]), b2 = ld16(pb[2]), b3 = ld16(pb[3]);
#pragma unroll
  for (int k0 = 0; k0 < K; k0 += 32) {
    short8v na0, na1, nb0, nb1, nb2, nb3;
    if (k0 + 32 < K) {
      na0 = ld16(pa0 + k0 + 32); na1 = ld16(pa1 + k0 + 32);
      nb0 = ld16(pb[0] + k0 + 32); nb1 = ld16(pb[1] + k0 + 32);
      nb2 = ld16(pb[2] + k0 + 32); nb3 = ld16(pb[3] + k0 + 32);
    }
    acc[0][0] = __builtin_amdgcn_mfma_f32_16x16x32_bf16(a0, b0, acc[0][0], 0, 0, 0);
    acc[1][0] = __builtin_amdgcn_mfma_f32_16x16x32_bf16(a1, b0, acc[1][0], 0, 0, 0);
    acc[0][1] = __builtin_amdgcn_mfma_f32_16x16x32_bf16(a0, b1, acc[0][1], 0, 0, 0);
    acc[1][1] = __builtin_amdgcn_mfma_f32_16x16x32_bf16(a1, b1, acc[1][1], 0, 0, 0);
    acc[0][2] = __builtin_amdgcn_mfma_f32_16x16x32_bf16(a0, b2, acc[0][2], 0, 0, 0);
    acc[1][2] = __builtin_amdgcn_mfma_f32_16x16x32_bf16(a1, b2, acc[1][2], 0, 0, 0);
    acc[0][3] = __builtin_amdgcn_mfma_f32_16x16x32_bf16(a0, b3, acc[0][3], 0, 0, 0);
    acc[1][3] = __builtin_amdgcn_mfma_f32_16x16x32_bf16(a1, b3, acc[1][3], 0, 0, 0);
    a0 = na0; a1 = na1; b0 = nb0; b1 = nb1; b2 = nb2; b3 = nb3;
  }
  // epilogue: C/D layout col=lane&15, row=(lane>>4)*4+q — fp8 store
#pragma unroll
  for (int m = 0; m < 2; ++m) {
    int rbase = row0 + wr * 32 + m * 16 + (l >> 4) * 4;
#pragma unroll
    for (int n = 0; n < 4; ++n) {
      int col = col0 + wc * 64 + n * 16 + lr;
#pragma unroll
      for (int q = 0; q < 4; ++q) {
        int row = rbase + q;
        if (row < M) Yc[(size_t)row * NC + col] = f2fp8(acc[m][n][q]);
      }
    }
  }
  // fused attention dots
  float asv[4], adv[4];
#pragma unroll
  for (int n = 0; n < 4; ++n) {
    int col = col0 + wc * 64 + n * 16 + lr;
    asv[n] = att_s[col];
    adv[n] = att_d[col];
  }
  float ps[2][4], pd[2][4];
#pragma unroll
  for (int m = 0; m < 2; ++m)
#pragma unroll
    for (int q = 0; q < 4; ++q) {
      float s = 0.f, d = 0.f;
#pragma unroll
      for (int n = 0; n < 4; ++n) {
        s = fmaf(acc[m][n][q], asv[n], s);
        d = fmaf(acc[m][n][q], adv[n], d);
      }
      ps[m][q] = s; pd[m][q] = d;
    }
#pragma unroll
  for (int o = 1; o < 16; o <<= 1) {
#pragma unroll
    for (int m = 0; m < 2; ++m)
#pragma unroll
      for (int q = 0; q < 4; ++q) {
        ps[m][q] += __shfl_xor(ps[m][q], o);
        pd[m][q] += __shfl_xor(pd[m][q], o);
      }
  }
  __syncthreads();
  if (wc == 1 && lr == 0) {
#pragma unroll
    for (int m = 0; m < 2; ++m)
#pragma unroll
      for (int q = 0; q < 4; ++q) {
        int rl = wr * 32 + m * 16 + (l >> 4) * 4 + q;
        sred[0][rl] = ps[m][q];
        sred[1][rl] = pd[m][q];
      }
  }
  __syncthreads();
  if (wc == 0 && lr == 0) {
#pragma unroll
    for (int m = 0; m < 2; ++m)
#pragma unroll
      for (int q = 0; q < 4; ++q) {
        int rl = wr * 32 + m * 16 + (l >> 4) * 4 + q;
        int row = row0 + rl;
        if (row < M) {
          So[(size_t)row * SST + by] = ps[m][q] + sred[0][rl];
          Do[(size_t)row * SST + by] = pd[m][q] + sred[1][rl];
        }
      }
  }
}

// ---------------- gemm1 + deg merged: blocks < gmx*3 do GEMM, rest do deg atomics ---------
__global__ __launch_bounds__(256) void gemm1_deg_kernel(const short* __restrict__ xb,
                                                        const __hip_bfloat16* __restrict__ Wt,
                                                        const float* __restrict__ att_s,
                                                        const float* __restrict__ att_d,
                                                        unsigned char* __restrict__ Yc,
                                                        float* __restrict__ So,
                                                        float* __restrict__ Do,
                                                        int M, int gmx,
                                                        const int* __restrict__ ed1,
                                                        const int* __restrict__ ed2,
                                                        int E, int Etot, int N,
                                                        int* __restrict__ deg) {
  __shared__ float sred[2][64];
  int bid = blockIdx.x;
  if (bid < gmx * 3) {
    gemm_body<256, 4>(bid % gmx, bid / gmx, xb, (const short*)Wt, att_s, att_d,
                      Yc, So, Do, M, 384, sred);
  } else {
    int idx = (bid - gmx * 3) * 256 + threadIdx.x;
    if (idx < 2 * Etot) {
      int br = idx >= Etot;
      int el = idx - br * Etot;
      const int* ed = br ? ed2 : ed1;
      int dn = ((el < E) ? ed[el] : (el - E)) + br * N;
      atomicAdd(&deg[dn], 1);
    }
  }
}

// ---------------- gemm2 + alpha merged: blocks < gmx do GEMM, rest write alpha ------------
__global__ __launch_bounds__(256) void gemm2_alpha_kernel(const short* __restrict__ e1b,
                                                          const __hip_bfloat16* __restrict__ Wt,
                                                          const float* __restrict__ att_s,
                                                          const float* __restrict__ att_d,
                                                          unsigned char* __restrict__ Yc,
                                                          float* __restrict__ So,
                                                          float* __restrict__ Do,
                                                          int M, int gmx,
                                                          const float* __restrict__ S4,
                                                          const float* __restrict__ D4,
                                                          const float* __restrict__ invden,
                                                          const int* __restrict__ es1,
                                                          const int* __restrict__ ed1,
                                                          const int* __restrict__ es2,
                                                          const int* __restrict__ ed2,
                                                          int E, int Etot, int N,
                                                          float* __restrict__ out) {
  __shared__ float sred[2][64];
  int bid = blockIdx.x;
  if (bid < gmx) {
    gemm_body<384, 1>(bid, 0, e1b, (const short*)Wt, att_s, att_d,
                      Yc, So, Do, M, 128, sred);
  } else {
    int idx = (bid - gmx) * 256 + threadIdx.x;
    if (idx < 2 * Etot) {
      int br = idx >= Etot;
      int el = idx - br * Etot;
      const int* es = br ? es2 : es1;
      const int* ed = br ? ed2 : ed1;
      int sn, dn;
      if (el < E) { sn = es[el]; dn = ed[el]; } else { sn = dn = el - E; }
      sn += br * N; dn += br * N;
      float* ao = out + 1 + (size_t)br * Etot * 3 + (size_t)el * 3;
#pragma unroll
      for (int h = 0; h < 3; ++h) {
        float v = lrelu(S4[sn * 4 + h] + D4[dn * 4 + h]);
        ao[h] = __expf(v) * invden[dn * 3 + h];
      }
    }
  }
}

// scan: thread-serial 20 elements + one block scan (n <= 20480)
__global__ __launch_bounds__(1024) void scan_kernel(const int* __restrict__ deg,
                                                    int* __restrict__ rowptr,
                                                    int* __restrict__ cursor, int n) {
  __shared__ int wsum[16];
  int t = threadIdx.x, lane = t & 63, wid = t >> 6;
  int start = t * 20;
  int v[20];
  int s = 0;
#pragma unroll
  for (int k = 0; k < 20; ++k) {
    int i = start + k;
    int d = (i < n) ? deg[i] : 0;
    s += d;
    v[k] = s;                    // inclusive local prefix
  }
  int x = s;
#pragma unroll
  for (int o = 1; o < 64; o <<= 1) {
    int tm = __shfl_up(x, o);
    if (lane >= o) x += tm;
  }
  if (lane == 63) wsum[wid] = x;
  __syncthreads();
  if (wid == 0) {
    int wv = (lane < 16) ? wsum[lane] : 0;
#pragma unroll
    for (int o = 1; o < 16; o <<= 1) {
      int tm = __shfl_up(wv, o);
      if (lane >= o) wv += tm;
    }
    if (lane < 16) wsum[lane] = wv;
  }
  __syncthreads();
  int excl = (x - s) + (wid ? wsum[wid - 1] : 0);
  if (t == 0) rowptr[0] = 0;
#pragma unroll
  for (int k = 0; k < 20; ++k) {
    int i = start + k;
    if (i < n) {
      rowptr[i + 1] = excl + v[k];
      cursor[i] = excl + (k ? v[k - 1] : 0);
    }
  }
}

// fill: minimal scatter — only csr_src (4 B/edge)
__global__ void fill_kernel(const int* __restrict__ es1, const int* __restrict__ ed1,
                            const int* __restrict__ es2, const int* __restrict__ ed2,
                            int E, int Etot, int N, int* __restrict__ cursor,
                            int* __restrict__ csr_src) {
  int idx = blockIdx.x * blockDim.x + threadIdx.x;
  if (idx >= 2 * Etot) return;
  int br = idx >= Etot;
  int el = idx - br * Etot;
  const int* es = br ? es2 : es1;
  const int* ed = br ? ed2 : ed1;
  int sn, dn;
  if (el < E) { sn = es[el]; dn = ed[el]; } else { sn = dn = el - E; }
  sn += br * N; dn += br * N;
  int pos = atomicAdd(&cursor[dn], 1);
  csr_src[pos] = sn;
}

// ---------------- agg1: ONE WAVE PER NODE, zero barriers --------------------------------
__global__ __launch_bounds__(256) void agg1_kernel(const unsigned char* __restrict__ h1c,
                                                   const float* __restrict__ S4,
                                                   const float* __restrict__ D4,
                                                   const int* __restrict__ rowptr,
                                                   const int* __restrict__ csr_src,
                                                   const float* __restrict__ b1,
                                                   __hip_bfloat16* __restrict__ e1b,
                                                   float* __restrict__ invden, int N2) {
  __shared__ float4 st[4][64];
  int wv = threadIdx.x >> 6;
  int n = blockIdx.x * 4 + wv;
  if (n >= N2) return;
  int l = threadIdx.x & 63;
  int head = l >> 5;                       // head of dword cols (0 or 1)
  const float4* S4v = reinterpret_cast<const float4*>(S4);
  int p0 = rowptr[n], p1 = rowptr[n + 1];
  float d0 = D4[n * 4], d1 = D4[n * 4 + 1], d2 = D4[n * 4 + 2];

  float dp0 = 0.f, dp1 = 0.f, dp2 = 0.f;
  float acc[6] = {0.f, 0.f, 0.f, 0.f, 0.f, 0.f};
  for (int base = p0; base < p1; base += 64) {
    int cnt = min(64, p1 - base);
    if (l < cnt) {
      int sn = csr_src[base + l];
      float4 sv = S4v[sn];
      float e0 = __expf(lrelu(sv.x + d0));
      float e1 = __expf(lrelu(sv.y + d1));
      float e2 = __expf(lrelu(sv.z + d2));
      st[wv][l] = make_float4(__int_as_float(sn), e0, e1, e2);
      dp0 += e0; dp1 += e1; dp2 += e2;
    }
    int i = 0;
    for (; i + 4 <= cnt; i += 4) {
      float4 w[4];
      unsigned int hv[4];
      unsigned short gv[4];
#pragma unroll
      for (int u = 0; u < 4; ++u) {
        w[u] = st[wv][i + u];
        int sn = __float_as_int(w[u].x);
        const unsigned char* row = h1c + (size_t)sn * 384;
        hv[u] = *reinterpret_cast<const unsigned int*>(row + 4 * l);
        gv[u] = *reinterpret_cast<const unsigned short*>(row + 256 + 2 * l);
      }
#pragma unroll
      for (int u = 0; u < 4; ++u) {
        float alo = head ? w[u].z : w[u].y;
        float ahi = w[u].w;
        f32x2 f0 = __builtin_amdgcn_cvt_pk_f32_fp8((int)hv[u], false);
        f32x2 f1 = __builtin_amdgcn_cvt_pk_f32_fp8((int)hv[u], true);
        f32x2 g0 = __builtin_amdgcn_cvt_pk_f32_fp8((int)(unsigned int)gv[u], false);
        acc[0] = fmaf(alo, f0.x, acc[0]);
        acc[1] = fmaf(alo, f0.y, acc[1]);
        acc[2] = fmaf(alo, f1.x, acc[2]);
        acc[3] = fmaf(alo, f1.y, acc[3]);
        acc[4] = fmaf(ahi, g0.x, acc[4]);
        acc[5] = fmaf(ahi, g0.y, acc[5]);
      }
    }
    for (; i < cnt; ++i) {
      float4 w = st[wv][i];
      int sn = __float_as_int(w.x);
      const unsigned char* row = h1c + (size_t)sn * 384;
      unsigned int hv = *reinterpret_cast<const unsigned int*>(row + 4 * l);
      unsigned short gv = *reinterpret_cast<const unsigned short*>(row + 256 + 2 * l);
      float alo = head ? w.z : w.y;
      float ahi = w.w;
      f32x2 f0 = __builtin_amdgcn_cvt_pk_f32_fp8((int)hv, false);
      f32x2 f1 = __builtin_amdgcn_cvt_pk_f32_fp8((int)hv, true);
      f32x2 g0 = __builtin_amdgcn_cvt_pk_f32_fp8((int)(unsigned int)gv, false);
      acc[0] = fmaf(alo, f0.x, acc[0]);
      acc[1] = fmaf(alo, f0.y, acc[1]);
      acc[2] = fmaf(alo, f1.x, acc[2]);
      acc[3] = fmaf(alo, f1.y, acc[3]);
      acc[4] = fmaf(ahi, g0.x, acc[4]);
      acc[5] = fmaf(ahi, g0.y, acc[5]);
    }
  }
#pragma unroll
  for (int o = 32; o; o >>= 1) {
    dp0 += __shfl_down(dp0, o); dp1 += __shfl_down(dp1, o); dp2 += __shfl_down(dp2, o);
  }
  float inv0 = 1.f / __shfl(dp0, 0);
  float inv1 = 1.f / __shfl(dp1, 0);
  float inv2 = 1.f / __shfl(dp2, 0);

  float ilo = head ? inv1 : inv0;
  int c0 = 4 * l;
  float4 bb = *reinterpret_cast<const float4*>(b1 + c0);
  float v0 = acc[0] * ilo + bb.x;
  float v1 = acc[1] * ilo + bb.y;
  float v2 = acc[2] * ilo + bb.z;
  float v3 = acc[3] * ilo + bb.w;
  v0 = v0 > 0.f ? v0 : 0.f; v1 = v1 > 0.f ? v1 : 0.f;
  v2 = v2 > 0.f ? v2 : 0.f; v3 = v3 > 0.f ? v3 : 0.f;
  int ch = 256 + 2 * l;
  float2 bh = *reinterpret_cast<const float2*>(b1 + ch);
  float v4 = acc[4] * inv2 + bh.x;
  float v5 = acc[5] * inv2 + bh.y;
  v4 = v4 > 0.f ? v4 : 0.f; v5 = v5 > 0.f ? v5 : 0.f;
  unsigned short* eb = reinterpret_cast<unsigned short*>(e1b) + (size_t)n * 384;
  uint2 lo;
  lo.x = (unsigned int)f2bf(v0) | ((unsigned int)f2bf(v1) << 16);
  lo.y = (unsigned int)f2bf(v2) | ((unsigned int)f2bf(v3) << 16);
  *reinterpret_cast<uint2*>(eb + c0) = lo;
  *reinterpret_cast<unsigned int*>(eb + ch) =
      (unsigned int)f2bf(v4) | ((unsigned int)f2bf(v5) << 16);
  if (l == 0) invden[n * 3] = inv0;
  else if (l == 1) invden[n * 3 + 1] = inv1;
  else if (l == 2) invden[n * 3 + 2] = inv2;
}

// ---------------- agg2: 4 nodes per block (1 wave each), wave-private staging -------------
__global__ __launch_bounds__(256) void agg2_kernel(const unsigned char* __restrict__ h2c,
                                                   const float* __restrict__ S2,
                                                   const float* __restrict__ D2,
                                                   const int* __restrict__ rowptr,
                                                   const int* __restrict__ csr_src,
                                                   const float* __restrict__ b2,
                                                   float* __restrict__ e2out, int N2) {
  __shared__ int lsrc[4][256];
  __shared__ float la[4][256];
  const unsigned int* H4 = reinterpret_cast<const unsigned int*>(h2c);
  int wv = threadIdx.x >> 6;
  int n = blockIdx.x * 4 + wv;
  if (n >= N2) return;
  int lane = threadIdx.x & 63;
  int half = lane >> 5, t = lane & 31;   // cols 4t..4t+3
  int p0 = rowptr[n], p1 = rowptr[n + 1];
  float dnv = D2[n];

  float dpart = 0.f;
  float acc[4] = {0.f, 0.f, 0.f, 0.f};
  for (int base = p0; base < p1; base += 256) {
    int cnt = min(256, p1 - base);
    for (int i = lane; i < cnt; i += 64) {
      int sn = csr_src[base + i];
      lsrc[wv][i] = sn;
      float ex = __expf(lrelu(S2[sn] + dnv));
      la[wv][i] = ex;
      dpart += ex;
    }
    int i = half;
    for (; i + 14 < cnt; i += 16) {
      unsigned int hv[8];
      float av[8];
#pragma unroll
      for (int u = 0; u < 8; ++u) {
        int e = i + 2 * u;
        int sn = lsrc[wv][e];
        av[u] = la[wv][e];
        hv[u] = H4[(size_t)sn * 32 + t];
      }
#pragma unroll
      for (int u = 0; u < 8; ++u) {
        f32x2 f0 = __builtin_amdgcn_cvt_pk_f32_fp8((int)hv[u], false);
        f32x2 f1 = __builtin_amdgcn_cvt_pk_f32_fp8((int)hv[u], true);
        acc[0] = fmaf(av[u], f0.x, acc[0]);
        acc[1] = fmaf(av[u], f0.y, acc[1]);
        acc[2] = fmaf(av[u], f1.x, acc[2]);
        acc[3] = fmaf(av[u], f1.y, acc[3]);
      }
    }
    for (; i < cnt; i += 2) {
      int sn = lsrc[wv][i];
      float a = la[wv][i];
      unsigned int hv = H4[(size_t)sn * 32 + t];
      f32x2 f0 = __builtin_amdgcn_cvt_pk_f32_fp8((int)hv, false);
      f32x2 f1 = __builtin_amdgcn_cvt_pk_f32_fp8((int)hv, true);
      acc[0] = fmaf(a, f0.x, acc[0]);
      acc[1] = fmaf(a, f0.y, acc[1]);
      acc[2] = fmaf(a, f1.x, acc[2]);
      acc[3] = fmaf(a, f1.y, acc[3]);
    }
  }
#pragma unroll
  for (int k = 0; k < 4; ++k) acc[k] += __shfl_xor(acc[k], 32);
#pragma unroll
  for (int o = 32; o; o >>= 1) dpart += __shfl_down(dpart, o);
  float invden = 1.f / __shfl(dpart, 0);
  if (half == 0) {
    float4 bb = *reinterpret_cast<const float4*>(b2 + 4 * t);
    float4 ov;
    ov.x = acc[0] * invden + bb.x;
    ov.y = acc[1] * invden + bb.y;
    ov.z = acc[2] * invden + bb.z;
    ov.w = acc[3] * invden + bb.w;
    *reinterpret_cast<float4*>(e2out + (size_t)n * 128 + 4 * t) = ov;
  }
}

// ---------------- pool + sim fused (last-block-done; coherent reads via atomicAdd+0) ------
__global__ __launch_bounds__(128) void pool_sim_kernel(const float* __restrict__ e2,
                                                       float* __restrict__ g,
                                                       int* __restrict__ cnt,
                                                       int N, float invN,
                                                       float* __restrict__ out) {
  int c = threadIdx.x;
  int br = blockIdx.y;
  int r0 = br * N + blockIdx.x * 128;
  int r1 = min(r0 + 128, br * N + N);
  float acc = 0.f;
  for (int n = r0; n < r1; ++n) acc += e2[(size_t)n * 128 + c];
  atomicAdd(&g[br * 128 + c], acc * invN);
  __threadfence();
  __shared__ bool last;
  __shared__ float sd[128], s1[128], s2[128];
  if (c == 0) {
    int total = gridDim.x * gridDim.y;
    last = (atomicAdd(cnt, 1) == total - 1);
  }
  __syncthreads();
  if (!last) return;
  float a = atomicAdd(&g[c], 0.f);         // coherent-point load
  float b = atomicAdd(&g[128 + c], 0.f);
  sd[c] = a * b; s1[c] = a * a; s2[c] = b * b;
  __syncthreads();
  for (int ofs = 64; ofs; ofs >>= 1) {
    if (c < ofs) { sd[c] += sd[c + ofs]; s1[c] += s1[c + ofs]; s2[c] += s2[c + ofs]; }
    __syncthreads();
  }
  if (c == 0) {
    float n1 = fmaxf(sqrtf(s1[0]), 1e-8f);
    float n2 = fmaxf(sqrtf(s2[0]), 1e-8f);
    out[0] = sd[0] / (n1 * n2);
  }
}

// ---------------- host ----------------
extern "C" void kernel_launch(void* const* d_in, const int* in_sizes, int n_in,
                              void* d_out, int out_size, void* d_ws, size_t ws_size,
                              hipStream_t stream) {
  const int N = in_sizes[0] / INDIM;
  const int E = in_sizes[1] / 2;
  const int Etot = E + N;
  const int N2 = 2 * N;

  const float* x1  = (const float*)d_in[0];
  const int*   ei1 = (const int*)d_in[1];
  const float* x2  = (const float*)d_in[2];
  const int*   ei2 = (const int*)d_in[3];
  const float* W1  = (const float*)d_in[4];
  const float* as1 = (const float*)d_in[5];
  const float* ad1 = (const float*)d_in[6];
  const float* b1  = (const float*)d_in[7];
  const float* W2  = (const float*)d_in[8];
  const float* as2 = (const float*)d_in[9];
  const float* ad2 = (const float*)d_in[10];
  const float* b2  = (const float*)d_in[11];
  float* out = (float*)d_out;
  const int* es1 = ei1, *ed1 = ei1 + E;
  const int* es2 = ei2, *ed2 = ei2 + E;

  char* p = (char*)d_ws;
  auto alloc = [&](size_t bytes) -> char* {
    char* q = p;
    p += (bytes + 255) & ~(size_t)255;
    return q;
  };
  // zero region: g (256f) | cnt (pad 256B) | deg (N2 ints) — one memset
  float* g   = (float*)alloc(256 * 4);
  int*   cnt = (int*)alloc(256);
  int*   deg = (int*)alloc((size_t)N2 * 4);
  size_t zero_bytes = (size_t)((char*)deg - (char*)g) + (((size_t)N2 * 4 + 255) & ~(size_t)255);

  unsigned short* xb = (unsigned short*)alloc((size_t)N2 * 256 * 2);
  unsigned char* h1c = (unsigned char*)alloc((size_t)N2 * 384);
  __hip_bfloat16* e1b = (__hip_bfloat16*)alloc((size_t)N2 * 384 * 2);
  unsigned char* h2c = (unsigned char*)alloc((size_t)N2 * 128);
  float* e2          = (float*)alloc((size_t)N2 * 128 * 4);
  __hip_bfloat16* W1t = (__hip_bfloat16*)alloc((size_t)256 * 384 * 2);
  __hip_bfloat16* W2t = (__hip_bfloat16*)alloc((size_t)384 * 128 * 2);
  float* s1v  = (float*)alloc((size_t)N2 * 4 * 4);   // stride-4 padded
  float* d1v  = (float*)alloc((size_t)N2 * 4 * 4);   // stride-4 padded
  float* s2v  = (float*)alloc((size_t)N2 * 4);
  float* d2v  = (float*)alloc((size_t)N2 * 4);
  float* idn  = (float*)alloc((size_t)N2 * 3 * 4);
  int* rowptr  = (int*)alloc((size_t)(N2 + 1) * 4);
  int* cursor  = (int*)alloc((size_t)N2 * 4);
  int* csr_src = (int*)alloc((size_t)2 * Etot * 4);

  const int EB = 256;
  const int egrid2 = (2 * Etot + EB - 1) / EB;
  const int gmx = (N2 + 63) / 64;
  const int wtot = 256 * 384 + 384 * 128 + N2 * 64;

  hipMemsetAsync(g, 0, zero_bytes, stream);
  wprep_kernel<<<(wtot + 255) / 256, 256, 0, stream>>>(W1, W1t, W2, W2t, x1, x2, xb, N);

  gemm1_deg_kernel<<<gmx * 3 + egrid2, 256, 0, stream>>>((const short*)xb, W1t, as1, ad1,
                                                         h1c, s1v, d1v, N2, gmx,
                                                         ed1, ed2, E, Etot, N, deg);
  scan_kernel<<<1, 1024, 0, stream>>>(deg, rowptr, cursor, N2);
  fill_kernel<<<egrid2, EB, 0, stream>>>(es1, ed1, es2, ed2, E, Etot, N, cursor, csr_src);

  agg1_kernel<<<(N2 + 3) / 4, 256, 0, stream>>>(h1c, s1v, d1v, rowptr, csr_src, b1,
                                                e1b, idn, N2);

  gemm2_alpha_kernel<<<gmx + egrid2, 256, 0, stream>>>((const short*)e1b, W2t, as2, ad2,
                                                       h2c, s2v, d2v, N2, gmx,
                                                       s1v, d1v, idn,
                                                       es1, ed1, es2, ed2, E, Etot, N, out);
  agg2_kernel<<<(N2 + 3) / 4, 256, 0, stream>>>(h2c, s2v, d2v, rowptr, csr_src, b2, e2, N2);

  pool_sim_kernel<<<dim3((N + 127) / 128, 2), 128, 0, stream>>>(e2, g, cnt, N,
                                                                1.f / (float)N, out);
}

// Round 18
// 220.628 us; speedup vs baseline: 1.0979x; 1.0979x over previous
//
#include <hip/hip_runtime.h>
#include <hip/hip_bf16.h>
#include <cstdint>
#include <cstddef>

#define INDIM 256
#define NEG 0.2f

typedef __attribute__((ext_vector_type(8))) short short8v;
typedef __attribute__((ext_vector_type(4))) float f32x4;
typedef __attribute__((ext_vector_type(2))) float f32x2;

__device__ __forceinline__ unsigned short f2bf(float x) {
  __hip_bfloat16 b = __float2bfloat16(x);
  return __builtin_bit_cast(unsigned short, b);
}

// native gfx950 fp8 (OCP E4M3) converts — single VALU instruction each
__device__ __forceinline__ unsigned char f2fp8(float v) {
  int packed = __builtin_amdgcn_cvt_pk_fp8_f32(v, v, 0, false);
  return (unsigned char)(packed & 0xff);
}

__device__ __forceinline__ float lrelu(float v) { return v > 0.f ? v : NEG * v; }

// ---------------- W pre-transpose to bf16 (both weights, one dispatch) --------------------
__global__ void wprep_kernel(const float* __restrict__ W1, __hip_bfloat16* __restrict__ W1t,
                             const float* __restrict__ W2, __hip_bfloat16* __restrict__ W2t) {
  int idx = blockIdx.x * blockDim.x + threadIdx.x;
  const int T1 = 256 * 384;
  if (idx < T1) {
    int k = idx / 384, c = idx - k * 384;
    W1t[(size_t)c * 256 + k] = __float2bfloat16(W1[idx]);
  } else {
    int i = idx - T1;
    if (i < 384 * 128) {
      int k = i / 128, c = i - k * 128;
      W2t[(size_t)c * 384 + k] = __float2bfloat16(W2[i]);
    }
  }
}

// ---------------- GEMM body (device fn): tile 64x128, 4 waves, fused attention dots ------
template<int K, bool ABF16, int SST>
__device__ __forceinline__ void gemm_body(int bx, int by,
                                          const void* __restrict__ A0,
                                          const void* __restrict__ A1, int Nsplit,
                                          const __hip_bfloat16* __restrict__ Wt,
                                          const float* __restrict__ att_s,
                                          const float* __restrict__ att_d,
                                          unsigned char* __restrict__ Yc,
                                          float* __restrict__ So,
                                          float* __restrict__ Do,
                                          int M, int NC,
                                          short (*As)[40], short (*Bs)[40],
                                          float (*sred)[64]) {
  const int tid = threadIdx.x;
  const int row0 = bx * 64;
  const int col0 = by * 128;
  const int l = tid & 63, w = tid >> 6;
  const int wr = w >> 1, wc = w & 1;
  const int lr = l & 15, lk = (l >> 4) * 8;

  f32x4 acc[2][4];
#pragma unroll
  for (int m = 0; m < 2; ++m)
#pragma unroll
    for (int n = 0; n < 4; ++n) acc[m][n] = {0.f, 0.f, 0.f, 0.f};

  for (int k0 = 0; k0 < K; k0 += 32) {
    __syncthreads();
    {  // stage A: 64 rows x 32 k
      int r = tid >> 2, kq = (tid & 3) * 8;
      int gr = row0 + r;
      short8v av = {0, 0, 0, 0, 0, 0, 0, 0};
      if (gr < M) {
        const void* Ab = (gr < Nsplit) ? A0 : A1;
        int lrow = (gr < Nsplit) ? gr : gr - Nsplit;
        if (ABF16) {
          av = *(const short8v*)((const short*)Ab + (size_t)lrow * K + k0 + kq);
        } else {
          const float* ap = (const float*)Ab + (size_t)lrow * K + k0 + kq;
          float4 u = *(const float4*)ap;
          float4 v = *(const float4*)(ap + 4);
          av = short8v{(short)f2bf(u.x), (short)f2bf(u.y), (short)f2bf(u.z), (short)f2bf(u.w),
                       (short)f2bf(v.x), (short)f2bf(v.y), (short)f2bf(v.z), (short)f2bf(v.w)};
        }
      }
      *(short8v*)&As[r][kq] = av;
    }
    {  // stage B: 128 cols x 32 k (Wt row-major [NC][K])
      int c = tid >> 1, kq = (tid & 1) * 8;
      const short* wp = (const short*)Wt + (size_t)(col0 + c) * K + k0 + kq;
      *(short8v*)&Bs[c][kq]      = *(const short8v*)wp;
      *(short8v*)&Bs[c][kq + 16] = *(const short8v*)(wp + 16);
    }
    __syncthreads();
    short8v a[2], b[4];
#pragma unroll
    for (int m = 0; m < 2; ++m) a[m] = *(short8v*)&As[wr * 32 + m * 16 + lr][lk];
#pragma unroll
    for (int n = 0; n < 4; ++n) b[n] = *(short8v*)&Bs[wc * 64 + n * 16 + lr][lk];
#pragma unroll
    for (int m = 0; m < 2; ++m)
#pragma unroll
      for (int n = 0; n < 4; ++n)
        acc[m][n] = __builtin_amdgcn_mfma_f32_16x16x32_bf16(a[m], b[n], acc[m][n], 0, 0, 0);
  }
  // epilogue: C/D layout col=lane&15, row=(lane>>4)*4+q — fp8 store
#pragma unroll
  for (int m = 0; m < 2; ++m) {
    int rbase = row0 + wr * 32 + m * 16 + (l >> 4) * 4;
#pragma unroll
    for (int n = 0; n < 4; ++n) {
      int col = col0 + wc * 64 + n * 16 + lr;
#pragma unroll
      for (int q = 0; q < 4; ++q) {
        int row = rbase + q;
        if (row < M) Yc[(size_t)row * NC + col] = f2fp8(acc[m][n][q]);
      }
    }
  }
  // fused attention dots
  float asv[4], adv[4];
#pragma unroll
  for (int n = 0; n < 4; ++n) {
    int col = col0 + wc * 64 + n * 16 + lr;
    asv[n] = att_s[col];
    adv[n] = att_d[col];
  }
  float ps[2][4], pd[2][4];
#pragma unroll
  for (int m = 0; m < 2; ++m)
#pragma unroll
    for (int q = 0; q < 4; ++q) {
      float s = 0.f, d = 0.f;
#pragma unroll
      for (int n = 0; n < 4; ++n) {
        s = fmaf(acc[m][n][q], asv[n], s);
        d = fmaf(acc[m][n][q], adv[n], d);
      }
      ps[m][q] = s; pd[m][q] = d;
    }
#pragma unroll
  for (int o = 1; o < 16; o <<= 1) {
#pragma unroll
    for (int m = 0; m < 2; ++m)
#pragma unroll
      for (int q = 0; q < 4; ++q) {
        ps[m][q] += __shfl_xor(ps[m][q], o);
        pd[m][q] += __shfl_xor(pd[m][q], o);
      }
  }
  __syncthreads();
  if (wc == 1 && lr == 0) {
#pragma unroll
    for (int m = 0; m < 2; ++m)
#pragma unroll
      for (int q = 0; q < 4; ++q) {
        int rl = wr * 32 + m * 16 + (l >> 4) * 4 + q;
        sred[0][rl] = ps[m][q];
        sred[1][rl] = pd[m][q];
      }
  }
  __syncthreads();
  if (wc == 0 && lr == 0) {
#pragma unroll
    for (int m = 0; m < 2; ++m)
#pragma unroll
      for (int q = 0; q < 4; ++q) {
        int rl = wr * 32 + m * 16 + (l >> 4) * 4 + q;
        int row = row0 + rl;
        if (row < M) {
          So[(size_t)row * SST + by] = ps[m][q] + sred[0][rl];
          Do[(size_t)row * SST + by] = pd[m][q] + sred[1][rl];
        }
      }
  }
}

// ---------------- gemm1 + deg merged: blocks < gmx*3 do GEMM, rest do deg atomics ---------
__global__ __launch_bounds__(256) void gemm1_deg_kernel(const float* __restrict__ x1,
                                                        const float* __restrict__ x2, int Nsplit,
                                                        const __hip_bfloat16* __restrict__ Wt,
                                                        const float* __restrict__ att_s,
                                                        const float* __restrict__ att_d,
                                                        unsigned char* __restrict__ Yc,
                                                        float* __restrict__ So,
                                                        float* __restrict__ Do,
                                                        int M, int gmx,
                                                        const int* __restrict__ ed1,
                                                        const int* __restrict__ ed2,
                                                        int E, int Etot, int N,
                                                        int* __restrict__ deg) {
  __shared__ short As[64][40];
  __shared__ short Bs[128][40];
  __shared__ float sred[2][64];
  int bid = blockIdx.x;
  if (bid < gmx * 3) {
    gemm_body<256, false, 4>(bid % gmx, bid / gmx, x1, x2, Nsplit, Wt, att_s, att_d,
                             Yc, So, Do, M, 384, As, Bs, sred);
  } else {
    int idx = (bid - gmx * 3) * 256 + threadIdx.x;
    if (idx < 2 * Etot) {
      int br = idx >= Etot;
      int el = idx - br * Etot;
      const int* ed = br ? ed2 : ed1;
      int dn = ((el < E) ? ed[el] : (el - E)) + br * N;
      atomicAdd(&deg[dn], 1);
    }
  }
}

// ---------------- gemm2 + alpha merged: blocks < gmx do GEMM, rest write alpha ------------
__global__ __launch_bounds__(256) void gemm2_alpha_kernel(const __hip_bfloat16* __restrict__ e1b,
                                                          const __hip_bfloat16* __restrict__ Wt,
                                                          const float* __restrict__ att_s,
                                                          const float* __restrict__ att_d,
                                                          unsigned char* __restrict__ Yc,
                                                          float* __restrict__ So,
                                                          float* __restrict__ Do,
                                                          int M, int gmx,
                                                          const float* __restrict__ S4,
                                                          const float* __restrict__ D4,
                                                          const float* __restrict__ invden,
                                                          const int* __restrict__ es1,
                                                          const int* __restrict__ ed1,
                                                          const int* __restrict__ es2,
                                                          const int* __restrict__ ed2,
                                                          int E, int Etot, int N,
                                                          float* __restrict__ out) {
  __shared__ short As[64][40];
  __shared__ short Bs[128][40];
  __shared__ float sred[2][64];
  int bid = blockIdx.x;
  if (bid < gmx) {
    gemm_body<384, true, 1>(bid, 0, e1b, e1b, M, Wt, att_s, att_d,
                            Yc, So, Do, M, 128, As, Bs, sred);
  } else {
    int idx = (bid - gmx) * 256 + threadIdx.x;
    if (idx < 2 * Etot) {
      int br = idx >= Etot;
      int el = idx - br * Etot;
      const int* es = br ? es2 : es1;
      const int* ed = br ? ed2 : ed1;
      int sn, dn;
      if (el < E) { sn = es[el]; dn = ed[el]; } else { sn = dn = el - E; }
      sn += br * N; dn += br * N;
      float* ao = out + 1 + (size_t)br * Etot * 3 + (size_t)el * 3;
#pragma unroll
      for (int h = 0; h < 3; ++h) {
        float v = lrelu(S4[sn * 4 + h] + D4[dn * 4 + h]);
        ao[h] = __expf(v) * invden[dn * 3 + h];
      }
    }
  }
}

// scan: thread-serial 20 elements + one block scan (n <= 20480)
__global__ __launch_bounds__(1024) void scan_kernel(const int* __restrict__ deg,
                                                    int* __restrict__ rowptr,
                                                    int* __restrict__ cursor, int n) {
  __shared__ int wsum[16];
  int t = threadIdx.x, lane = t & 63, wid = t >> 6;
  int start = t * 20;
  int v[20];
  int s = 0;
#pragma unroll
  for (int k = 0; k < 20; ++k) {
    int i = start + k;
    int d = (i < n) ? deg[i] : 0;
    s += d;
    v[k] = s;                    // inclusive local prefix
  }
  int x = s;
#pragma unroll
  for (int o = 1; o < 64; o <<= 1) {
    int tm = __shfl_up(x, o);
    if (lane >= o) x += tm;
  }
  if (lane == 63) wsum[wid] = x;
  __syncthreads();
  if (wid == 0) {
    int wv = (lane < 16) ? wsum[lane] : 0;
#pragma unroll
    for (int o = 1; o < 16; o <<= 1) {
      int tm = __shfl_up(wv, o);
      if (lane >= o) wv += tm;
    }
    if (lane < 16) wsum[lane] = wv;
  }
  __syncthreads();
  int excl = (x - s) + (wid ? wsum[wid - 1] : 0);
  if (t == 0) rowptr[0] = 0;
#pragma unroll
  for (int k = 0; k < 20; ++k) {
    int i = start + k;
    if (i < n) {
      rowptr[i + 1] = excl + v[k];
      cursor[i] = excl + (k ? v[k - 1] : 0);
    }
  }
}

// fill: minimal scatter — only csr_src (4 B/edge)
__global__ void fill_kernel(const int* __restrict__ es1, const int* __restrict__ ed1,
                            const int* __restrict__ es2, const int* __restrict__ ed2,
                            int E, int Etot, int N, int* __restrict__ cursor,
                            int* __restrict__ csr_src) {
  int idx = blockIdx.x * blockDim.x + threadIdx.x;
  if (idx >= 2 * Etot) return;
  int br = idx >= Etot;
  int el = idx - br * Etot;
  const int* es = br ? es2 : es1;
  const int* ed = br ? ed2 : ed1;
  int sn, dn;
  if (el < E) { sn = es[el]; dn = ed[el]; } else { sn = dn = el - E; }
  sn += br * N; dn += br * N;
  int pos = atomicAdd(&cursor[dn], 1);
  csr_src[pos] = sn;
}

// ---------------- agg1: ONE WAVE PER NODE, zero barriers --------------------------------
__global__ __launch_bounds__(256) void agg1_kernel(const unsigned char* __restrict__ h1c,
                                                   const float* __restrict__ S4,
                                                   const float* __restrict__ D4,
                                                   const int* __restrict__ rowptr,
                                                   const int* __restrict__ csr_src,
                                                   const float* __restrict__ b1,
                                                   __hip_bfloat16* __restrict__ e1b,
                                                   float* __restrict__ invden, int N2) {
  __shared__ float4 st[4][64];
  int wv = threadIdx.x >> 6;
  int n = blockIdx.x * 4 + wv;
  if (n >= N2) return;
  int l = threadIdx.x & 63;
  int head = l >> 5;                       // head of dword cols (0 or 1)
  const float4* S4v = reinterpret_cast<const float4*>(S4);
  int p0 = rowptr[n], p1 = rowptr[n + 1];
  float d0 = D4[n * 4], d1 = D4[n * 4 + 1], d2 = D4[n * 4 + 2];

  float dp0 = 0.f, dp1 = 0.f, dp2 = 0.f;
  float acc[6] = {0.f, 0.f, 0.f, 0.f, 0.f, 0.f};
  for (int base = p0; base < p1; base += 64) {
    int cnt = min(64, p1 - base);
    if (l < cnt) {
      int sn = csr_src[base + l];
      float4 sv = S4v[sn];
      float e0 = __expf(lrelu(sv.x + d0));
      float e1 = __expf(lrelu(sv.y + d1));
      float e2 = __expf(lrelu(sv.z + d2));
      st[wv][l] = make_float4(__int_as_float(sn), e0, e1, e2);
      dp0 += e0; dp1 += e1; dp2 += e2;
    }
    int i = 0;
    for (; i + 4 <= cnt; i += 4) {
      float4 w[4];
      unsigned int hv[4];
      unsigned short gv[4];
#pragma unroll
      for (int u = 0; u < 4; ++u) {
        w[u] = st[wv][i + u];
        int sn = __float_as_int(w[u].x);
        const unsigned char* row = h1c + (size_t)sn * 384;
        hv[u] = *reinterpret_cast<const unsigned int*>(row + 4 * l);
        gv[u] = *reinterpret_cast<const unsigned short*>(row + 256 + 2 * l);
      }
#pragma unroll
      for (int u = 0; u < 4; ++u) {
        float alo = head ? w[u].z : w[u].y;
        float ahi = w[u].w;
        f32x2 f0 = __builtin_amdgcn_cvt_pk_f32_fp8((int)hv[u], false);
        f32x2 f1 = __builtin_amdgcn_cvt_pk_f32_fp8((int)hv[u], true);
        f32x2 g0 = __builtin_amdgcn_cvt_pk_f32_fp8((int)(unsigned int)gv[u], false);
        acc[0] = fmaf(alo, f0.x, acc[0]);
        acc[1] = fmaf(alo, f0.y, acc[1]);
        acc[2] = fmaf(alo, f1.x, acc[2]);
        acc[3] = fmaf(alo, f1.y, acc[3]);
        acc[4] = fmaf(ahi, g0.x, acc[4]);
        acc[5] = fmaf(ahi, g0.y, acc[5]);
      }
    }
    for (; i < cnt; ++i) {
      float4 w = st[wv][i];
      int sn = __float_as_int(w.x);
      const unsigned char* row = h1c + (size_t)sn * 384;
      unsigned int hv = *reinterpret_cast<const unsigned int*>(row + 4 * l);
      unsigned short gv = *reinterpret_cast<const unsigned short*>(row + 256 + 2 * l);
      float alo = head ? w.z : w.y;
      float ahi = w.w;
      f32x2 f0 = __builtin_amdgcn_cvt_pk_f32_fp8((int)hv, false);
      f32x2 f1 = __builtin_amdgcn_cvt_pk_f32_fp8((int)hv, true);
      f32x2 g0 = __builtin_amdgcn_cvt_pk_f32_fp8((int)(unsigned int)gv, false);
      acc[0] = fmaf(alo, f0.x, acc[0]);
      acc[1] = fmaf(alo, f0.y, acc[1]);
      acc[2] = fmaf(alo, f1.x, acc[2]);
      acc[3] = fmaf(alo, f1.y, acc[3]);
      acc[4] = fmaf(ahi, g0.x, acc[4]);
      acc[5] = fmaf(ahi, g0.y, acc[5]);
    }
  }
#pragma unroll
  for (int o = 32; o; o >>= 1) {
    dp0 += __shfl_down(dp0, o); dp1 += __shfl_down(dp1, o); dp2 += __shfl_down(dp2, o);
  }
  float inv0 = 1.f / __shfl(dp0, 0);
  float inv1 = 1.f / __shfl(dp1, 0);
  float inv2 = 1.f / __shfl(dp2, 0);

  float ilo = head ? inv1 : inv0;
  int c0 = 4 * l;
  float4 bb = *reinterpret_cast<const float4*>(b1 + c0);
  float v0 = acc[0] * ilo + bb.x;
  float v1 = acc[1] * ilo + bb.y;
  float v2 = acc[2] * ilo + bb.z;
  float v3 = acc[3] * ilo + bb.w;
  v0 = v0 > 0.f ? v0 : 0.f; v1 = v1 > 0.f ? v1 : 0.f;
  v2 = v2 > 0.f ? v2 : 0.f; v3 = v3 > 0.f ? v3 : 0.f;
  int ch = 256 + 2 * l;
  float2 bh = *reinterpret_cast<const float2*>(b1 + ch);
  float v4 = acc[4] * inv2 + bh.x;
  float v5 = acc[5] * inv2 + bh.y;
  v4 = v4 > 0.f ? v4 : 0.f; v5 = v5 > 0.f ? v5 : 0.f;
  unsigned short* eb = reinterpret_cast<unsigned short*>(e1b) + (size_t)n * 384;
  uint2 lo;
  lo.x = (unsigned int)f2bf(v0) | ((unsigned int)f2bf(v1) << 16);
  lo.y = (unsigned int)f2bf(v2) | ((unsigned int)f2bf(v3) << 16);
  *reinterpret_cast<uint2*>(eb + c0) = lo;
  *reinterpret_cast<unsigned int*>(eb + ch) =
      (unsigned int)f2bf(v4) | ((unsigned int)f2bf(v5) << 16);
  if (l == 0) invden[n * 3] = inv0;
  else if (l == 1) invden[n * 3 + 1] = inv1;
  else if (l == 2) invden[n * 3 + 2] = inv2;
}

// ---------------- agg2: 4 nodes per block (1 wave each), wave-private staging -------------
__global__ __launch_bounds__(256) void agg2_kernel(const unsigned char* __restrict__ h2c,
                                                   const float* __restrict__ S2,
                                                   const float* __restrict__ D2,
                                                   const int* __restrict__ rowptr,
                                                   const int* __restrict__ csr_src,
                                                   const float* __restrict__ b2,
                                                   float* __restrict__ e2out, int N2) {
  __shared__ int lsrc[4][256];
  __shared__ float la[4][256];
  const unsigned int* H4 = reinterpret_cast<const unsigned int*>(h2c);
  int wv = threadIdx.x >> 6;
  int n = blockIdx.x * 4 + wv;
  if (n >= N2) return;
  int lane = threadIdx.x & 63;
  int half = lane >> 5, t = lane & 31;   // cols 4t..4t+3
  int p0 = rowptr[n], p1 = rowptr[n + 1];
  float dnv = D2[n];

  float dpart = 0.f;
  float acc[4] = {0.f, 0.f, 0.f, 0.f};
  for (int base = p0; base < p1; base += 256) {
    int cnt = min(256, p1 - base);
    for (int i = lane; i < cnt; i += 64) {
      int sn = csr_src[base + i];
      lsrc[wv][i] = sn;
      float ex = __expf(lrelu(S2[sn] + dnv));
      la[wv][i] = ex;
      dpart += ex;
    }
    int i = half;
    for (; i + 14 < cnt; i += 16) {
      unsigned int hv[8];
      float av[8];
#pragma unroll
      for (int u = 0; u < 8; ++u) {
        int e = i + 2 * u;
        int sn = lsrc[wv][e];
        av[u] = la[wv][e];
        hv[u] = H4[(size_t)sn * 32 + t];
      }
#pragma unroll
      for (int u = 0; u < 8; ++u) {
        f32x2 f0 = __builtin_amdgcn_cvt_pk_f32_fp8((int)hv[u], false);
        f32x2 f1 = __builtin_amdgcn_cvt_pk_f32_fp8((int)hv[u], true);
        acc[0] = fmaf(av[u], f0.x, acc[0]);
        acc[1] = fmaf(av[u], f0.y, acc[1]);
        acc[2] = fmaf(av[u], f1.x, acc[2]);
        acc[3] = fmaf(av[u], f1.y, acc[3]);
      }
    }
    for (; i < cnt; i += 2) {
      int sn = lsrc[wv][i];
      float a = la[wv][i];
      unsigned int hv = H4[(size_t)sn * 32 + t];
      f32x2 f0 = __builtin_amdgcn_cvt_pk_f32_fp8((int)hv, false);
      f32x2 f1 = __builtin_amdgcn_cvt_pk_f32_fp8((int)hv, true);
      acc[0] = fmaf(a, f0.x, acc[0]);
      acc[1] = fmaf(a, f0.y, acc[1]);
      acc[2] = fmaf(a, f1.x, acc[2]);
      acc[3] = fmaf(a, f1.y, acc[3]);
    }
  }
#pragma unroll
  for (int k = 0; k < 4; ++k) acc[k] += __shfl_xor(acc[k], 32);
#pragma unroll
  for (int o = 32; o; o >>= 1) dpart += __shfl_down(dpart, o);
  float invden = 1.f / __shfl(dpart, 0);
  if (half == 0) {
    float4 bb = *reinterpret_cast<const float4*>(b2 + 4 * t);
    float4 ov;
    ov.x = acc[0] * invden + bb.x;
    ov.y = acc[1] * invden + bb.y;
    ov.z = acc[2] * invden + bb.z;
    ov.w = acc[3] * invden + bb.w;
    *reinterpret_cast<float4*>(e2out + (size_t)n * 128 + 4 * t) = ov;
  }
}

// ---------------- pool + sim fused (last-block-done; coherent reads via atomicAdd+0) ------
__global__ __launch_bounds__(128) void pool_sim_kernel(const float* __restrict__ e2,
                                                       float* __restrict__ g,
                                                       int* __restrict__ cnt,
                                                       int N, float invN,
                                                       float* __restrict__ out) {
  int c = threadIdx.x;
  int br = blockIdx.y;
  int r0 = br * N + blockIdx.x * 128;
  int r1 = min(r0 + 128, br * N + N);
  float acc = 0.f;
  for (int n = r0; n < r1; ++n) acc += e2[(size_t)n * 128 + c];
  atomicAdd(&g[br * 128 + c], acc * invN);
  __threadfence();
  __shared__ bool last;
  __shared__ float sd[128], s1[128], s2[128];
  if (c == 0) {
    int total = gridDim.x * gridDim.y;
    last = (atomicAdd(cnt, 1) == total - 1);
  }
  __syncthreads();
  if (!last) return;
  float a = atomicAdd(&g[c], 0.f);         // coherent-point load
  float b = atomicAdd(&g[128 + c], 0.f);
  sd[c] = a * b; s1[c] = a * a; s2[c] = b * b;
  __syncthreads();
  for (int ofs = 64; ofs; ofs >>= 1) {
    if (c < ofs) { sd[c] += sd[c + ofs]; s1[c] += s1[c + ofs]; s2[c] += s2[c + ofs]; }
    __syncthreads();
  }
  if (c == 0) {
    float n1 = fmaxf(sqrtf(s1[0]), 1e-8f);
    float n2 = fmaxf(sqrtf(s2[0]), 1e-8f);
    out[0] = sd[0] / (n1 * n2);
  }
}

// ---------------- host ----------------
extern "C" void kernel_launch(void* const* d_in, const int* in_sizes, int n_in,
                              void* d_out, int out_size, void* d_ws, size_t ws_size,
                              hipStream_t stream) {
  const int N = in_sizes[0] / INDIM;
  const int E = in_sizes[1] / 2;
  const int Etot = E + N;
  const int N2 = 2 * N;

  const float* x1  = (const float*)d_in[0];
  const int*   ei1 = (const int*)d_in[1];
  const float* x2  = (const float*)d_in[2];
  const int*   ei2 = (const int*)d_in[3];
  const float* W1  = (const float*)d_in[4];
  const float* as1 = (const float*)d_in[5];
  const float* ad1 = (const float*)d_in[6];
  const float* b1  = (const float*)d_in[7];
  const float* W2  = (const float*)d_in[8];
  const float* as2 = (const float*)d_in[9];
  const float* ad2 = (const float*)d_in[10];
  const float* b2  = (const float*)d_in[11];
  float* out = (float*)d_out;
  const int* es1 = ei1, *ed1 = ei1 + E;
  const int* es2 = ei2, *ed2 = ei2 + E;

  char* p = (char*)d_ws;
  auto alloc = [&](size_t bytes) -> char* {
    char* q = p;
    p += (bytes + 255) & ~(size_t)255;
    return q;
  };
  // zero region: g (256f) | cnt (pad 256B) | deg (N2 ints) — one memset
  float* g   = (float*)alloc(256 * 4);
  int*   cnt = (int*)alloc(256);
  int*   deg = (int*)alloc((size_t)N2 * 4);
  size_t zero_bytes = (size_t)((char*)deg - (char*)g) + (((size_t)N2 * 4 + 255) & ~(size_t)255);

  unsigned char* h1c = (unsigned char*)alloc((size_t)N2 * 384);
  __hip_bfloat16* e1b = (__hip_bfloat16*)alloc((size_t)N2 * 384 * 2);
  unsigned char* h2c = (unsigned char*)alloc((size_t)N2 * 128);
  float* e2          = (float*)alloc((size_t)N2 * 128 * 4);
  __hip_bfloat16* W1t = (__hip_bfloat16*)alloc((size_t)256 * 384 * 2);
  __hip_bfloat16* W2t = (__hip_bfloat16*)alloc((size_t)384 * 128 * 2);
  float* s1v  = (float*)alloc((size_t)N2 * 4 * 4);   // stride-4 padded
  float* d1v  = (float*)alloc((size_t)N2 * 4 * 4);   // stride-4 padded
  float* s2v  = (float*)alloc((size_t)N2 * 4);
  float* d2v  = (float*)alloc((size_t)N2 * 4);
  float* idn  = (float*)alloc((size_t)N2 * 3 * 4);
  int* rowptr  = (int*)alloc((size_t)(N2 + 1) * 4);
  int* cursor  = (int*)alloc((size_t)N2 * 4);
  int* csr_src = (int*)alloc((size_t)2 * Etot * 4);

  const int EB = 256;
  const int egrid2 = (2 * Etot + EB - 1) / EB;
  const int gmx = (N2 + 63) / 64;

  hipMemsetAsync(g, 0, zero_bytes, stream);
  wprep_kernel<<<(256 * 384 + 384 * 128 + 255) / 256, 256, 0, stream>>>(W1, W1t, W2, W2t);

  gemm1_deg_kernel<<<gmx * 3 + egrid2, 256, 0, stream>>>(x1, x2, N, W1t, as1, ad1,
                                                         h1c, s1v, d1v, N2, gmx,
                                                         ed1, ed2, E, Etot, N, deg);
  scan_kernel<<<1, 1024, 0, stream>>>(deg, rowptr, cursor, N2);
  fill_kernel<<<egrid2, EB, 0, stream>>>(es1, ed1, es2, ed2, E, Etot, N, cursor, csr_src);

  agg1_kernel<<<(N2 + 3) / 4, 256, 0, stream>>>(h1c, s1v, d1v, rowptr, csr_src, b1,
                                                e1b, idn, N2);

  gemm2_alpha_kernel<<<gmx + egrid2, 256, 0, stream>>>(e1b, W2t, as2, ad2,
                                                       h2c, s2v, d2v, N2, gmx,
                                                       s1v, d1v, idn,
                                                       es1, ed1, es2, ed2, E, Etot, N, out);
  agg2_kernel<<<(N2 + 3) / 4, 256, 0, stream>>>(h2c, s2v, d2v, rowptr, csr_src, b2, e2, N2);

  pool_sim_kernel<<<dim3((N + 127) / 128, 2), 128, 0, stream>>>(e2, g, cnt, N,
                                                                1.f / (float)N, out);
}